// Round 1
// baseline (735.079 us; speedup 1.0000x reference)
//
#include <hip/hip_runtime.h>

typedef unsigned short u16;
typedef __attribute__((ext_vector_type(4))) float f32x4;
typedef __attribute__((ext_vector_type(8))) short short8;

__device__ __forceinline__ u16 f2b(float f) {
    unsigned u = __float_as_uint(f);
    u += 0x7fff + ((u >> 16) & 1);
    return (u16)(u >> 16);
}

// XOR swizzle for 128-byte-row LDS tiles: moves 16B chunk within the row by row&7
__device__ __forceinline__ int swz(int byteoff) {
    return byteoff ^ (((byteoff >> 7) & 7) << 4);
}

// ---------------------------------------------------------------------------
// Weight packing: W[z][1024][64] -> out rows (voff + h*64 + k), cols d (bf16)
// ---------------------------------------------------------------------------
__global__ __launch_bounds__(256) void pack_wkv_t(const float* __restrict__ W,
                                                  u16* __restrict__ out, int voff) {
    __shared__ float tile[32][33];
    int z = blockIdx.z; int l = z >> 4, h = z & 15;
    const float* ip = W + (size_t)z * 1024 * 64;
    u16* op = out + (size_t)l * 2048 * 1024 + (size_t)(voff + h * 64) * 1024;
    int tx = threadIdx.x & 31, ty = threadIdx.x >> 5;
    int d0 = blockIdx.y * 32, k0 = blockIdx.x * 32;
#pragma unroll
    for (int j = 0; j < 32; j += 8)
        tile[ty + j][tx] = ip[(size_t)(d0 + ty + j) * 64 + k0 + tx];
    __syncthreads();
#pragma unroll
    for (int j = 0; j < 32; j += 8)
        op[(size_t)(k0 + ty + j) * 1024 + d0 + tx] = f2b(tile[tx][ty + j]);
}

// Generic transpose+convert: in[z][R][C] fp32 -> out[z][C][R] bf16
__global__ __launch_bounds__(256) void transpose_cvt(const float* __restrict__ in,
                                                     u16* __restrict__ out, int R, int C) {
    __shared__ float tile[32][33];
    const float* ip = in + (size_t)blockIdx.z * R * C;
    u16* op = out + (size_t)blockIdx.z * R * C;
    int tx = threadIdx.x & 31, ty = threadIdx.x >> 5;
    int r0 = blockIdx.y * 32, c0 = blockIdx.x * 32;
#pragma unroll
    for (int j = 0; j < 32; j += 8)
        tile[ty + j][tx] = ip[(size_t)(r0 + ty + j) * C + c0 + tx];
    __syncthreads();
#pragma unroll
    for (int j = 0; j < 32; j += 8)
        op[(size_t)(c0 + ty + j) * R + r0 + tx] = f2b(tile[tx][ty + j]);
}

__global__ __launch_bounds__(256) void cvt_bf16(const float* __restrict__ in,
                                                u16* __restrict__ out, int n) {
    int i = (blockIdx.x * 256 + threadIdx.x) * 4;
    if (i >= n) return;
    float4 v = *(const float4*)&in[i];
    ushort4 o = {f2b(v.x), f2b(v.y), f2b(v.z), f2b(v.w)};
    *(ushort4*)&out[i] = o;
}

// ---------------------------------------------------------------------------
// GEMM: C[M][N] = A[M][K]bf16 @ B[N][K]bf16^T (+bias, epilogue)
// EPI 0: bf16 out, bias1/bias2 split at `split`, cols<split scaled by 0.125
// EPI 1: fp32 out, bias + relu
// EPI 2: fp32 out, bias
// 128x128 tile, BK=32, 4 waves (2x2), each 4x4 of 16x16x32 mfma
// LDS layout: k-chunk-major [4 chunks][128 rows][8 elems]
// ---------------------------------------------------------------------------
template <int EPI>
__global__ __launch_bounds__(256) void gemm_bt(const u16* __restrict__ A,
                                               const u16* __restrict__ B,
                                               const float* __restrict__ bias1,
                                               const float* __restrict__ bias2, int split,
                                               void* __restrict__ Cv, int M, int N, int K) {
    __shared__ __align__(16) u16 lA[4 * 128 * 8];
    __shared__ __align__(16) u16 lB[4 * 128 * 8];
    const int t = threadIdx.x;
    const int lane = t & 63, w = t >> 6;
    const int wr = w >> 1, wc = w & 1;
    const int g = lane >> 4, r = lane & 15;
    const int m0 = blockIdx.y * 128, n0 = blockIdx.x * 128;

    f32x4 zero4 = {0.f, 0.f, 0.f, 0.f};
    f32x4 acc[4][4];
#pragma unroll
    for (int m = 0; m < 4; ++m)
#pragma unroll
        for (int n = 0; n < 4; ++n) acc[m][n] = zero4;

    const int srow = t >> 2, sc = t & 3;
    const u16* Ap = A + (size_t)(m0 + srow) * K + sc * 8;
    const u16* Bp = B + (size_t)(n0 + srow) * K + sc * 8;
    u16* lAw = &lA[(sc * 128 + srow) * 8];
    u16* lBw = &lB[(sc * 128 + srow) * 8];

    for (int k0 = 0; k0 < K; k0 += 32) {
        uint4 a0 = *(const uint4*)(Ap + k0);
        uint4 a1 = *(const uint4*)(Ap + k0 + (size_t)64 * K);
        uint4 b0 = *(const uint4*)(Bp + k0);
        uint4 b1 = *(const uint4*)(Bp + k0 + (size_t)64 * K);
        __syncthreads();
        *(uint4*)lAw = a0;
        *(uint4*)(lAw + 64 * 8) = a1;
        *(uint4*)lBw = b0;
        *(uint4*)(lBw + 64 * 8) = b1;
        __syncthreads();
        short8 af[4], bf[4];
#pragma unroll
        for (int m = 0; m < 4; ++m)
            af[m] = *(const short8*)&lA[(g * 128 + wr * 64 + m * 16 + r) * 8];
#pragma unroll
        for (int n = 0; n < 4; ++n)
            bf[n] = *(const short8*)&lB[(g * 128 + wc * 64 + n * 16 + r) * 8];
#pragma unroll
        for (int m = 0; m < 4; ++m)
#pragma unroll
            for (int n = 0; n < 4; ++n)
                acc[m][n] = __builtin_amdgcn_mfma_f32_16x16x32_bf16(af[m], bf[n], acc[m][n], 0, 0, 0);
    }

#pragma unroll
    for (int m = 0; m < 4; ++m) {
        int row = m0 + wr * 64 + m * 16 + g * 4;
#pragma unroll
        for (int n = 0; n < 4; ++n) {
            int col = n0 + wc * 64 + n * 16 + r;
            float bv_ = (col < split) ? bias1[col] : bias2[col - split];
#pragma unroll
            for (int i = 0; i < 4; ++i) {
                float v = acc[m][n][i] + bv_;
                if (EPI == 0) {
                    v *= (col < split) ? 0.125f : 1.0f;
                    ((u16*)Cv)[(size_t)(row + i) * N + col] = f2b(v);
                } else if (EPI == 1) {
                    ((float*)Cv)[(size_t)(row + i) * N + col] = fmaxf(v, 0.f);
                } else {
                    ((float*)Cv)[(size_t)(row + i) * N + col] = v;
                }
            }
        }
    }
}

// ---------------------------------------------------------------------------
// Flash-style attention (quirk: Q := K-proj, keys/values := V-proj)
// KV[token][0..1023] = K-proj (pre-scaled by 0.125), [1024..2047] = V-proj
// Block: (b,h,qb) -> 64 q-rows; 4 waves x 16 rows; loop over 16 kv tiles of 64
// ---------------------------------------------------------------------------
__global__ __launch_bounds__(256) void attn_kernel(const u16* __restrict__ KV,
                                                   float* __restrict__ Out) {
    __shared__ __align__(16) u16 qt[64 * 64];
    __shared__ __align__(16) u16 kt[64 * 64];
    __shared__ __align__(16) u16 vt[64 * 72];   // transposed [d][key], padded rows
    __shared__ __align__(16) u16 pt[4][16 * 64];
    const int t = threadIdx.x;
    const int lane = t & 63, w = t >> 6;
    const int g = lane >> 4, r = lane & 15;
    const int qb = blockIdx.x & 15;
    const int bh = blockIdx.x >> 4;
    const int h = bh & 15, b = bh >> 4;
    const u16* Kbase = KV + (size_t)b * 1024 * 2048 + h * 64;
    const u16* Vbase = Kbase + 1024;

    // load Q tile (swizzled 128B rows)
    for (int idx = t; idx < 512; idx += 256) {
        int row = idx >> 3, cb = (idx & 7) * 16;
        uint4 d4 = *(const uint4*)&Kbase[(size_t)(qb * 64 + row) * 2048 + (idx & 7) * 8];
        *(uint4*)((char*)qt + swz(row * 128 + cb)) = d4;
    }
    float m_i[4], l_i[4];
    f32x4 zero4 = {0.f, 0.f, 0.f, 0.f};
    f32x4 oacc[4];
#pragma unroll
    for (int i = 0; i < 4; ++i) { m_i[i] = -1e30f; l_i[i] = 0.f; }
#pragma unroll
    for (int n = 0; n < 4; ++n) oacc[n] = zero4;
    __syncthreads();

    for (int t0 = 0; t0 < 1024; t0 += 64) {
        // stage key/value tile: kt row-major swizzled, vt transposed padded
        for (int idx = t; idx < 512; idx += 256) {
            int row = idx >> 3, c8 = (idx & 7) * 8;
            uint4 d4 = *(const uint4*)&Vbase[(size_t)(t0 + row) * 2048 + c8];
            *(uint4*)((char*)kt + swz(row * 128 + c8 * 2)) = d4;
            vt[(c8 + 0) * 72 + row] = (u16)(d4.x);
            vt[(c8 + 1) * 72 + row] = (u16)(d4.x >> 16);
            vt[(c8 + 2) * 72 + row] = (u16)(d4.y);
            vt[(c8 + 3) * 72 + row] = (u16)(d4.y >> 16);
            vt[(c8 + 4) * 72 + row] = (u16)(d4.z);
            vt[(c8 + 5) * 72 + row] = (u16)(d4.z >> 16);
            vt[(c8 + 6) * 72 + row] = (u16)(d4.w);
            vt[(c8 + 7) * 72 + row] = (u16)(d4.w >> 16);
        }
        __syncthreads();
        // S = Q @ K^T  (16 q-rows per wave x 64 keys)
        f32x4 sf[4];
#pragma unroll
        for (int n = 0; n < 4; ++n) sf[n] = zero4;
#pragma unroll
        for (int ks = 0; ks < 2; ++ks) {
            short8 a = *(const short8*)((char*)qt + swz((w * 16 + r) * 128 + ks * 64 + g * 16));
#pragma unroll
            for (int n = 0; n < 4; ++n) {
                short8 bb = *(const short8*)((char*)kt + swz((n * 16 + r) * 128 + ks * 64 + g * 16));
                sf[n] = __builtin_amdgcn_mfma_f32_16x16x32_bf16(a, bb, sf[n], 0, 0, 0);
            }
        }
        // online softmax (row = g*4+i, cols spread over 16 lanes of same g)
#pragma unroll
        for (int i = 0; i < 4; ++i) {
            float rm = fmaxf(fmaxf(sf[0][i], sf[1][i]), fmaxf(sf[2][i], sf[3][i]));
#pragma unroll
            for (int off = 1; off < 16; off <<= 1) rm = fmaxf(rm, __shfl_xor(rm, off, 64));
            float mn = fmaxf(m_i[i], rm);
            float c = __expf(m_i[i] - mn);
            float rs = 0.f;
#pragma unroll
            for (int n = 0; n < 4; ++n) {
                float p0 = __expf(sf[n][i] - mn);
                sf[n][i] = p0;
                rs += p0;
            }
#pragma unroll
            for (int off = 1; off < 16; off <<= 1) rs += __shfl_xor(rs, off, 64);
            l_i[i] = l_i[i] * c + rs;
            m_i[i] = mn;
#pragma unroll
            for (int n = 0; n < 4; ++n) oacc[n][i] *= c;
        }
        // P -> LDS (wave-private, swizzled), C-layout write
        char* ptw = (char*)&pt[w][0];
#pragma unroll
        for (int n = 0; n < 4; ++n)
#pragma unroll
            for (int i = 0; i < 4; ++i)
                *(u16*)(ptw + swz((g * 4 + i) * 128 + (n * 16 + r) * 2)) = f2b(sf[n][i]);
        __syncthreads();
        // O += P @ V
#pragma unroll
        for (int ks = 0; ks < 2; ++ks) {
            short8 a = *(const short8*)(ptw + swz(r * 128 + ks * 64 + g * 16));
#pragma unroll
            for (int n = 0; n < 4; ++n) {
                short8 bb = *(const short8*)&vt[(n * 16 + r) * 72 + ks * 32 + g * 8];
                oacc[n] = __builtin_amdgcn_mfma_f32_16x16x32_bf16(a, bb, oacc[n], 0, 0, 0);
            }
        }
        __syncthreads();
    }
#pragma unroll
    for (int n = 0; n < 4; ++n) {
        int col = h * 64 + n * 16 + r;
#pragma unroll
        for (int i = 0; i < 4; ++i) {
            int row = qb * 64 + w * 16 + g * 4 + i;
            Out[((size_t)b * 1024 + row) * 1024 + col] = oacc[n][i] / l_i[i];
        }
    }
}

// ---------------------------------------------------------------------------
// Fused residual + LayerNorm; writes fp32 x and bf16 x
// ---------------------------------------------------------------------------
__global__ __launch_bounds__(256) void ln_kernel(const float* __restrict__ xin,
                                                 const float* __restrict__ addin,
                                                 const float* __restrict__ gamma,
                                                 const float* __restrict__ beta,
                                                 float* __restrict__ xout,
                                                 u16* __restrict__ xbout) {
    const int row = blockIdx.x, t = threadIdx.x;
    const size_t base = (size_t)row * 1024;
    float4 xv = *(const float4*)&xin[base + t * 4];
    float4 av = *(const float4*)&addin[base + t * 4];
    float v0 = xv.x + av.x, v1 = xv.y + av.y, v2 = xv.z + av.z, v3 = xv.w + av.w;
    float s = v0 + v1 + v2 + v3;
    __shared__ float red[4];
    const int lane = t & 63, w = t >> 6;
#pragma unroll
    for (int off = 32; off; off >>= 1) s += __shfl_xor(s, off, 64);
    if (lane == 0) red[w] = s;
    __syncthreads();
    float mean = (red[0] + red[1] + red[2] + red[3]) * (1.f / 1024.f);
    __syncthreads();
    float d0 = v0 - mean, d1 = v1 - mean, d2 = v2 - mean, d3 = v3 - mean;
    float sq = d0 * d0 + d1 * d1 + d2 * d2 + d3 * d3;
#pragma unroll
    for (int off = 32; off; off >>= 1) sq += __shfl_xor(sq, off, 64);
    if (lane == 0) red[w] = sq;
    __syncthreads();
    float var = (red[0] + red[1] + red[2] + red[3]) * (1.f / 1024.f);
    float rstd = rsqrtf(var + 1e-5f);
    float4 gv = *(const float4*)&gamma[t * 4];
    float4 bv = *(const float4*)&beta[t * 4];
    float o0 = d0 * rstd * gv.x + bv.x;
    float o1 = d1 * rstd * gv.y + bv.y;
    float o2 = d2 * rstd * gv.z + bv.z;
    float o3 = d3 * rstd * gv.w + bv.w;
    float4 ov = {o0, o1, o2, o3};
    *(float4*)&xout[base + t * 4] = ov;
    ushort4 q = {f2b(o0), f2b(o1), f2b(o2), f2b(o3)};
    *(ushort4*)&xbout[base + t * 4] = q;
}

// ---------------------------------------------------------------------------
extern "C" void kernel_launch(void* const* d_in, const int* in_sizes, int n_in,
                              void* d_out, int out_size, void* d_ws, size_t ws_size,
                              hipStream_t stream) {
    const float* x  = (const float*)d_in[0];
    const float* Wk = (const float*)d_in[1];
    const float* bk = (const float*)d_in[2];
    const float* Wv = (const float*)d_in[3];
    const float* bv = (const float*)d_in[4];
    const float* Wl = (const float*)d_in[5];
    const float* bl = (const float*)d_in[6];
    const float* g1 = (const float*)d_in[7];
    const float* b1 = (const float*)d_in[8];
    const float* g2 = (const float*)d_in[9];
    const float* b2 = (const float*)d_in[10];
    const float* Wo = (const float*)d_in[11];
    const float* bo = (const float*)d_in[12];

    char* ws = (char*)d_ws;
    u16* Wkvb = (u16*)ws;  ws += (size_t)4 * 2048 * 1024 * 2;
    u16* Wlb  = (u16*)ws;  ws += (size_t)4 * 1024 * 1024 * 2;
    u16* Wob  = (u16*)ws;  ws += (size_t)1024 * 1024 * 2;
    u16* xb   = (u16*)ws;  ws += (size_t)4096 * 1024 * 2;
    u16* KVb  = (u16*)ws;  ws += (size_t)4096 * 2048 * 2;
    float* xf   = (float*)ws;  ws += (size_t)4096 * 1024 * 4;
    float* tmpf = (float*)ws;  ws += (size_t)4096 * 1024 * 4;

    pack_wkv_t<<<dim3(2, 32, 64), 256, 0, stream>>>(Wk, Wkvb, 0);
    pack_wkv_t<<<dim3(2, 32, 64), 256, 0, stream>>>(Wv, Wkvb, 1024);
    transpose_cvt<<<dim3(32, 32, 4), 256, 0, stream>>>(Wl, Wlb, 1024, 1024);
    transpose_cvt<<<dim3(32, 32, 1), 256, 0, stream>>>(Wo, Wob, 1024, 1024);
    cvt_bf16<<<dim3(4096), 256, 0, stream>>>(x, xb, 4096 * 1024);

    for (int l = 0; l < 4; ++l) {
        gemm_bt<0><<<dim3(16, 32), 256, 0, stream>>>(
            xb, Wkvb + (size_t)l * 2048 * 1024, bk + l * 1024, bv + l * 1024, 1024,
            (void*)KVb, 4096, 2048, 1024);
        attn_kernel<<<dim3(1024), 256, 0, stream>>>(KVb, tmpf);
        ln_kernel<<<dim3(4096), 256, 0, stream>>>(
            (l == 0 ? x : xf), tmpf, g1 + l * 1024, b1 + l * 1024, xf, xb);
        gemm_bt<1><<<dim3(8, 32), 256, 0, stream>>>(
            xb, Wlb + (size_t)l * 1024 * 1024, bl + l * 1024, bl + l * 1024, 1024,
            (void*)tmpf, 4096, 1024, 1024);
        ln_kernel<<<dim3(4096), 256, 0, stream>>>(
            xf, tmpf, g2 + l * 1024, b2 + l * 1024, xf, xb);
    }
    gemm_bt<2><<<dim3(8, 32), 256, 0, stream>>>(
        xb, Wob, bo, bo, 1024, d_out, 4096, 1024, 1024);
}

// Round 2
// 663.165 us; speedup vs baseline: 1.1084x; 1.1084x over previous
//
#include <hip/hip_runtime.h>

typedef unsigned short u16;
typedef __attribute__((ext_vector_type(4))) float f32x4;
typedef __attribute__((ext_vector_type(8))) short short8;

__device__ __forceinline__ u16 f2b(float f) {
    unsigned u = __float_as_uint(f);
    u += 0x7fff + ((u >> 16) & 1);
    return (u16)(u >> 16);
}
__device__ __forceinline__ float b2f(u16 v) {
    return __uint_as_float(((unsigned)v) << 16);
}
// XOR swizzle for 128-byte-row LDS tiles
__device__ __forceinline__ int swz(int byteoff) {
    return byteoff ^ (((byteoff >> 7) & 7) << 4);
}
// async global->LDS, 16B per lane; l must be wave-uniform (lane adds l*16)
__device__ __forceinline__ void gl16(const u16* g, u16* l) {
    __builtin_amdgcn_global_load_lds(
        (const __attribute__((address_space(1))) unsigned*)(g),
        (__attribute__((address_space(3))) unsigned*)(l), 16, 0, 0);
}

// ---------------------------------------------------------------------------
// Weight packing: W[z][1024][64] -> out rows (voff + h*64 + k), cols d (bf16)
// ---------------------------------------------------------------------------
__global__ __launch_bounds__(256) void pack_wkv_t(const float* __restrict__ W,
                                                  u16* __restrict__ out, int voff) {
    __shared__ float tile[32][33];
    int z = blockIdx.z; int l = z >> 4, h = z & 15;
    const float* ip = W + (size_t)z * 1024 * 64;
    u16* op = out + (size_t)l * 2048 * 1024 + (size_t)(voff + h * 64) * 1024;
    int tx = threadIdx.x & 31, ty = threadIdx.x >> 5;
    int d0 = blockIdx.y * 32, k0 = blockIdx.x * 32;
#pragma unroll
    for (int j = 0; j < 32; j += 8)
        tile[ty + j][tx] = ip[(size_t)(d0 + ty + j) * 64 + k0 + tx];
    __syncthreads();
#pragma unroll
    for (int j = 0; j < 32; j += 8)
        op[(size_t)(k0 + ty + j) * 1024 + d0 + tx] = f2b(tile[tx][ty + j]);
}

__global__ __launch_bounds__(256) void transpose_cvt(const float* __restrict__ in,
                                                     u16* __restrict__ out, int R, int C) {
    __shared__ float tile[32][33];
    const float* ip = in + (size_t)blockIdx.z * R * C;
    u16* op = out + (size_t)blockIdx.z * R * C;
    int tx = threadIdx.x & 31, ty = threadIdx.x >> 5;
    int r0 = blockIdx.y * 32, c0 = blockIdx.x * 32;
#pragma unroll
    for (int j = 0; j < 32; j += 8)
        tile[ty + j][tx] = ip[(size_t)(r0 + ty + j) * C + c0 + tx];
    __syncthreads();
#pragma unroll
    for (int j = 0; j < 32; j += 8)
        op[(size_t)(c0 + ty + j) * R + r0 + tx] = f2b(tile[tx][ty + j]);
}

__global__ __launch_bounds__(256) void cvt_bf16(const float* __restrict__ in,
                                                u16* __restrict__ out, int n) {
    int i = (blockIdx.x * 256 + threadIdx.x) * 4;
    if (i >= n) return;
    float4 v = *(const float4*)&in[i];
    ushort4 o = {f2b(v.x), f2b(v.y), f2b(v.z), f2b(v.w)};
    *(ushort4*)&out[i] = o;
}

// ---------------------------------------------------------------------------
// GEMM: C[M][N] = A[M][K]bf16 @ B[N][K]bf16^T (+bias, epilogue)
// EPI 0: bf16 out (KV), K cols scaled 0.125; also writes V^T tile to VTout
// EPI 1: bf16 out, bias + relu
// EPI 2: fp32 out, bias
// tile 128 x BN, BK=32, 4 waves, global_load_lds staging into chunk-major LDS
// ---------------------------------------------------------------------------
template <int EPI, int BN>
__global__ __launch_bounds__(256) void gemm_bt(const u16* __restrict__ A,
                                               const u16* __restrict__ B,
                                               const float* __restrict__ bias1,
                                               const float* __restrict__ bias2, int split,
                                               void* __restrict__ Cv,
                                               u16* __restrict__ VTout,
                                               int M, int N, int K) {
    constexpr int NB = BN / 32;
    __shared__ __align__(16) u16 lA[512 * 8];
    __shared__ __align__(16) u16 lB[4 * BN * 8];
    const int t = threadIdx.x;
    const int lane = t & 63, w = t >> 6;
    const int wr = w >> 1, wc = w & 1;
    const int g = lane >> 4, r = lane & 15;
    const int m0 = blockIdx.y * 128, n0 = blockIdx.x * BN;

    // staging map: LDS chunk c (16B) holds A[m0 + (c&127)][k0 + (c>>7)*8 ..]
    const int cA1 = w * 64 + lane;
    const int cA2 = 256 + cA1;
    const u16* Ap1 = A + (size_t)(m0 + (cA1 & 127)) * K + (cA1 >> 7) * 8;
    const u16* Ap2 = A + (size_t)(m0 + (cA2 & 127)) * K + (cA2 >> 7) * 8;
    const u16* Bp1 = B + (size_t)(n0 + (cA1 & (BN - 1))) * K + (cA1 / BN) * 8;
    const u16* Bp2 = B + (size_t)(n0 + (cA2 & (BN - 1))) * K + (cA2 / BN) * 8;
    u16* lAd1 = lA + (w * 64) * 8;
    u16* lAd2 = lA + (256 + w * 64) * 8;
    u16* lBd1 = lB + (w * 64) * 8;
    u16* lBd2 = lB + (256 + w * 64) * 8;

    f32x4 zero4 = {0.f, 0.f, 0.f, 0.f};
    f32x4 acc[4][NB];
#pragma unroll
    for (int m = 0; m < 4; ++m)
#pragma unroll
        for (int n = 0; n < NB; ++n) acc[m][n] = zero4;

    for (int k0 = 0; k0 < K; k0 += 32) {
        __syncthreads();
        gl16(Ap1 + k0, lAd1);
        gl16(Ap2 + k0, lAd2);
        gl16(Bp1 + k0, lBd1);
        if constexpr (BN == 128) gl16(Bp2 + k0, lBd2);
        __syncthreads();
        short8 af[4], bf[NB];
#pragma unroll
        for (int m = 0; m < 4; ++m)
            af[m] = *(const short8*)&lA[(g * 128 + wr * 64 + m * 16 + r) * 8];
#pragma unroll
        for (int n = 0; n < NB; ++n)
            bf[n] = *(const short8*)&lB[(g * BN + wc * (BN / 2) + n * 16 + r) * 8];
#pragma unroll
        for (int m = 0; m < 4; ++m)
#pragma unroll
            for (int n = 0; n < NB; ++n)
                acc[m][n] = __builtin_amdgcn_mfma_f32_16x16x32_bf16(af[m], bf[n], acc[m][n], 0, 0, 0);
    }

#pragma unroll
    for (int m = 0; m < 4; ++m) {
        int row = m0 + wr * 64 + m * 16 + g * 4;
#pragma unroll
        for (int n = 0; n < NB; ++n) {
            int col = n0 + wc * (BN / 2) + n * 16 + r;
            float bv_ = (col < split) ? bias1[col] : bias2[col - split];
            if (EPI == 0) {
                float sc = (col < split) ? 0.125f : 1.0f;
                ushort4 qv;
                qv.x = f2b((acc[m][n][0] + bv_) * sc);
                qv.y = f2b((acc[m][n][1] + bv_) * sc);
                qv.z = f2b((acc[m][n][2] + bv_) * sc);
                qv.w = f2b((acc[m][n][3] + bv_) * sc);
                u16* Cb = (u16*)Cv;
                Cb[(size_t)(row + 0) * N + col] = qv.x;
                Cb[(size_t)(row + 1) * N + col] = qv.y;
                Cb[(size_t)(row + 2) * N + col] = qv.z;
                Cb[(size_t)(row + 3) * N + col] = qv.w;
                if (col >= split) {
                    int d = col - split, b_ = row >> 10, s = row & 1023;
                    *(ushort4*)&VTout[(((size_t)(b_ * 16) + (d >> 6)) * 64 + (d & 63)) * 1024 + s] = qv;
                }
            } else if (EPI == 1) {
                u16* Cb = (u16*)Cv;
#pragma unroll
                for (int i = 0; i < 4; ++i)
                    Cb[(size_t)(row + i) * N + col] = f2b(fmaxf(acc[m][n][i] + bv_, 0.f));
            } else {
#pragma unroll
                for (int i = 0; i < 4; ++i)
                    ((float*)Cv)[(size_t)(row + i) * N + col] = acc[m][n][i] + bv_;
            }
        }
    }
}

// ---------------------------------------------------------------------------
// Flash-style attention (quirk: Q := K-proj pre-scaled, keys/values := V-proj)
// KV[token][0..1023]=K-proj, [1024..2047]=V-proj; VT[b][h][d][token]=V^T
// Block: (b,h,qb) -> 64 q-rows; 4 waves x 16 rows; 16 kv tiles of 64
// All tiles DMA-staged via global_load_lds with source-side XOR swizzle.
// ---------------------------------------------------------------------------
__global__ __launch_bounds__(256) void attn_kernel(const u16* __restrict__ KV,
                                                   const u16* __restrict__ VT,
                                                   u16* __restrict__ Out) {
    __shared__ __align__(16) u16 qt[512 * 8];
    __shared__ __align__(16) u16 kt[512 * 8];
    __shared__ __align__(16) u16 vt[512 * 8];
    __shared__ __align__(16) u16 pt[4][16 * 64];
    const int t = threadIdx.x;
    const int lane = t & 63, w = t >> 6;
    const int g = lane >> 4, r = lane & 15;
    const int qb = blockIdx.x & 15;
    const int bh = blockIdx.x >> 4;
    const int h = bh & 15, b = bh >> 4;
    const u16* Kbase = KV + (size_t)b * 1024 * 2048 + h * 64;
    const u16* Vbase = Kbase + 1024;
    const u16* VTbase = VT + ((size_t)(b * 16 + h)) * 64 * 1024;

    // staging map: chunk c -> logical (row=c>>3, 16B-chunk c&7); source col
    // pre-swizzled so linear DMA + swz() reads agree
    const int c1 = w * 64 + lane, c2 = 256 + c1;
    const int row1 = c1 >> 3, row2 = c2 >> 3;
    const int col1 = (((c1 & 7) * 16) ^ ((row1 & 7) << 4)) >> 1;  // u16 offset
    const int col2 = (((c2 & 7) * 16) ^ ((row2 & 7) << 4)) >> 1;
    u16* qtd1 = qt + (w * 64) * 8;       u16* qtd2 = qt + (256 + w * 64) * 8;
    u16* ktd1 = kt + (w * 64) * 8;       u16* ktd2 = kt + (256 + w * 64) * 8;
    u16* vtd1 = vt + (w * 64) * 8;       u16* vtd2 = vt + (256 + w * 64) * 8;

    gl16(Kbase + (size_t)(qb * 64 + row1) * 2048 + col1, qtd1);
    gl16(Kbase + (size_t)(qb * 64 + row2) * 2048 + col2, qtd2);
    const u16* Kt1 = Vbase + (size_t)row1 * 2048 + col1;
    const u16* Kt2 = Vbase + (size_t)row2 * 2048 + col2;
    const u16* Vt1 = VTbase + (size_t)row1 * 1024 + col1;
    const u16* Vt2 = VTbase + (size_t)row2 * 1024 + col2;

    float m_i[4], l_i[4];
    f32x4 zero4 = {0.f, 0.f, 0.f, 0.f};
    f32x4 oacc[4];
#pragma unroll
    for (int i = 0; i < 4; ++i) { m_i[i] = -1e30f; l_i[i] = 0.f; }
#pragma unroll
    for (int n = 0; n < 4; ++n) oacc[n] = zero4;

    char* ptw = (char*)&pt[w][0];
    for (int t0 = 0; t0 < 1024; t0 += 64) {
        __syncthreads();   // previous tile fully consumed
        gl16(Kt1 + (size_t)t0 * 2048, ktd1);
        gl16(Kt2 + (size_t)t0 * 2048, ktd2);
        gl16(Vt1 + t0, vtd1);
        gl16(Vt2 + t0, vtd2);
        __syncthreads();   // staged (vmcnt drained at barrier)
        // S = Q @ K^T
        f32x4 sf[4];
#pragma unroll
        for (int n = 0; n < 4; ++n) sf[n] = zero4;
#pragma unroll
        for (int ks = 0; ks < 2; ++ks) {
            short8 a = *(const short8*)((char*)qt + swz((w * 16 + r) * 128 + ks * 64 + g * 16));
#pragma unroll
            for (int n = 0; n < 4; ++n) {
                short8 bb = *(const short8*)((char*)kt + swz((n * 16 + r) * 128 + ks * 64 + g * 16));
                sf[n] = __builtin_amdgcn_mfma_f32_16x16x32_bf16(a, bb, sf[n], 0, 0, 0);
            }
        }
        // online softmax (row = g*4+i, cols spread over the 16 lanes sharing g)
#pragma unroll
        for (int i = 0; i < 4; ++i) {
            float rm = fmaxf(fmaxf(sf[0][i], sf[1][i]), fmaxf(sf[2][i], sf[3][i]));
#pragma unroll
            for (int off = 1; off < 16; off <<= 1) rm = fmaxf(rm, __shfl_xor(rm, off, 64));
            float mn = fmaxf(m_i[i], rm);
            float c = __expf(m_i[i] - mn);
            float rs = 0.f;
#pragma unroll
            for (int n = 0; n < 4; ++n) {
                float p0 = __expf(sf[n][i] - mn);
                sf[n][i] = p0;
                rs += p0;
            }
#pragma unroll
            for (int off = 1; off < 16; off <<= 1) rs += __shfl_xor(rs, off, 64);
            l_i[i] = l_i[i] * c + rs;
            m_i[i] = mn;
#pragma unroll
            for (int n = 0; n < 4; ++n) oacc[n][i] *= c;
        }
        // P -> wave-private LDS (swizzled); intra-wave lgkmcnt ordering only
#pragma unroll
        for (int n = 0; n < 4; ++n)
#pragma unroll
            for (int i = 0; i < 4; ++i)
                *(u16*)(ptw + swz((g * 4 + i) * 128 + (n * 16 + r) * 2)) = f2b(sf[n][i]);
        // O += P @ V
#pragma unroll
        for (int ks = 0; ks < 2; ++ks) {
            short8 a = *(const short8*)(ptw + swz(r * 128 + ks * 64 + g * 16));
#pragma unroll
            for (int n = 0; n < 4; ++n) {
                short8 bb = *(const short8*)((char*)vt + swz((n * 16 + r) * 128 + ks * 64 + g * 16));
                oacc[n] = __builtin_amdgcn_mfma_f32_16x16x32_bf16(a, bb, oacc[n], 0, 0, 0);
            }
        }
    }
#pragma unroll
    for (int i = 0; i < 4; ++i) l_i[i] = 1.f / l_i[i];
#pragma unroll
    for (int n = 0; n < 4; ++n) {
        int col = h * 64 + n * 16 + r;
#pragma unroll
        for (int i = 0; i < 4; ++i) {
            int row = qb * 64 + w * 16 + g * 4 + i;
            Out[((size_t)b * 1024 + row) * 1024 + col] = f2b(oacc[n][i] * l_i[i]);
        }
    }
}

// ---------------------------------------------------------------------------
// Fused residual + LayerNorm; residual addend is bf16; writes fp32 + bf16 x
// ---------------------------------------------------------------------------
__global__ __launch_bounds__(256) void ln_kernel(const float* __restrict__ xin,
                                                 const u16* __restrict__ addin,
                                                 const float* __restrict__ gamma,
                                                 const float* __restrict__ beta,
                                                 float* __restrict__ xout,
                                                 u16* __restrict__ xbout) {
    const int row = blockIdx.x, t = threadIdx.x;
    const size_t base = (size_t)row * 1024;
    float4 xv = *(const float4*)&xin[base + t * 4];
    ushort4 au = *(const ushort4*)&addin[base + t * 4];
    float v0 = xv.x + b2f(au.x), v1 = xv.y + b2f(au.y);
    float v2 = xv.z + b2f(au.z), v3 = xv.w + b2f(au.w);
    float s = v0 + v1 + v2 + v3;
    __shared__ float red[4];
    const int lane = t & 63, w = t >> 6;
#pragma unroll
    for (int off = 32; off; off >>= 1) s += __shfl_xor(s, off, 64);
    if (lane == 0) red[w] = s;
    __syncthreads();
    float mean = (red[0] + red[1] + red[2] + red[3]) * (1.f / 1024.f);
    __syncthreads();
    float d0 = v0 - mean, d1 = v1 - mean, d2 = v2 - mean, d3 = v3 - mean;
    float sq = d0 * d0 + d1 * d1 + d2 * d2 + d3 * d3;
#pragma unroll
    for (int off = 32; off; off >>= 1) sq += __shfl_xor(sq, off, 64);
    if (lane == 0) red[w] = sq;
    __syncthreads();
    float var = (red[0] + red[1] + red[2] + red[3]) * (1.f / 1024.f);
    float rstd = rsqrtf(var + 1e-5f);
    float4 gv = *(const float4*)&gamma[t * 4];
    float4 bv = *(const float4*)&beta[t * 4];
    float o0 = d0 * rstd * gv.x + bv.x;
    float o1 = d1 * rstd * gv.y + bv.y;
    float o2 = d2 * rstd * gv.z + bv.z;
    float o3 = d3 * rstd * gv.w + bv.w;
    float4 ov = {o0, o1, o2, o3};
    *(float4*)&xout[base + t * 4] = ov;
    ushort4 q = {f2b(o0), f2b(o1), f2b(o2), f2b(o3)};
    *(ushort4*)&xbout[base + t * 4] = q;
}

// ---------------------------------------------------------------------------
extern "C" void kernel_launch(void* const* d_in, const int* in_sizes, int n_in,
                              void* d_out, int out_size, void* d_ws, size_t ws_size,
                              hipStream_t stream) {
    const float* x  = (const float*)d_in[0];
    const float* Wk = (const float*)d_in[1];
    const float* bk = (const float*)d_in[2];
    const float* Wv = (const float*)d_in[3];
    const float* bv = (const float*)d_in[4];
    const float* Wl = (const float*)d_in[5];
    const float* bl = (const float*)d_in[6];
    const float* g1 = (const float*)d_in[7];
    const float* b1 = (const float*)d_in[8];
    const float* g2 = (const float*)d_in[9];
    const float* b2 = (const float*)d_in[10];
    const float* Wo = (const float*)d_in[11];
    const float* bo = (const float*)d_in[12];

    char* ws = (char*)d_ws;
    u16* Wkvb = (u16*)ws;  ws += (size_t)4 * 2048 * 1024 * 2;   // 16 MB
    u16* Wlb  = (u16*)ws;  ws += (size_t)4 * 1024 * 1024 * 2;   //  8 MB
    u16* Wob  = (u16*)ws;  ws += (size_t)1024 * 1024 * 2;       //  2 MB
    u16* xb   = (u16*)ws;  ws += (size_t)4096 * 1024 * 2;       //  8 MB
    u16* KVb  = (u16*)ws;  ws += (size_t)4096 * 2048 * 2;       // 16 MB
    u16* VTb  = (u16*)ws;  ws += (size_t)4096 * 1024 * 2;       //  8 MB
    u16* tmpb = (u16*)ws;  ws += (size_t)4096 * 1024 * 2;       //  8 MB
    float* xf = (float*)ws; ws += (size_t)4096 * 1024 * 4;      // 16 MB

    pack_wkv_t<<<dim3(2, 32, 64), 256, 0, stream>>>(Wk, Wkvb, 0);
    pack_wkv_t<<<dim3(2, 32, 64), 256, 0, stream>>>(Wv, Wkvb, 1024);
    transpose_cvt<<<dim3(32, 32, 4), 256, 0, stream>>>(Wl, Wlb, 1024, 1024);
    transpose_cvt<<<dim3(32, 32, 1), 256, 0, stream>>>(Wo, Wob, 1024, 1024);
    cvt_bf16<<<dim3(4096), 256, 0, stream>>>(x, xb, 4096 * 1024);

    for (int l = 0; l < 4; ++l) {
        gemm_bt<0, 128><<<dim3(16, 32), 256, 0, stream>>>(
            xb, Wkvb + (size_t)l * 2048 * 1024, bk + l * 1024, bv + l * 1024, 1024,
            (void*)KVb, VTb, 4096, 2048, 1024);
        attn_kernel<<<dim3(1024), 256, 0, stream>>>(KVb, VTb, tmpb);
        ln_kernel<<<dim3(4096), 256, 0, stream>>>(
            (l == 0 ? x : xf), tmpb, g1 + l * 1024, b1 + l * 1024, xf, xb);
        gemm_bt<1, 64><<<dim3(16, 32), 256, 0, stream>>>(
            xb, Wlb + (size_t)l * 1024 * 1024, bl + l * 1024, bl + l * 1024, 1024,
            (void*)tmpb, nullptr, 4096, 1024, 1024);
        ln_kernel<<<dim3(4096), 256, 0, stream>>>(
            xf, tmpb, g2 + l * 1024, b2 + l * 1024, xf, xb);
    }
    gemm_bt<2, 64><<<dim3(16, 32), 256, 0, stream>>>(
        xb, Wob, bo, bo, 1024, d_out, nullptr, 4096, 1024, 1024);
}

// Round 3
// 502.538 us; speedup vs baseline: 1.4627x; 1.3196x over previous
//
#include <hip/hip_runtime.h>

typedef unsigned short u16;
typedef unsigned int u32;
typedef __attribute__((ext_vector_type(4))) float f32x4;
typedef __attribute__((ext_vector_type(8))) short short8;

#if __has_builtin(__builtin_amdgcn_exp2f)
#define EXP2(x) __builtin_amdgcn_exp2f(x)
#else
#define EXP2(x) exp2f(x)
#endif

// 1/sqrt(64) * log2(e): K-proj pre-scale so softmax runs in exp2 domain
#define SCALEK 0.18033688011112042f

__device__ __forceinline__ u16 f2b(float f) {
    unsigned u = __float_as_uint(f);
    u += 0x7fff + ((u >> 16) & 1);
    return (u16)(u >> 16);
}
__device__ __forceinline__ float b2f(u16 v) {
    return __uint_as_float(((unsigned)v) << 16);
}
// XOR swizzle for 128-byte-row LDS tiles
__device__ __forceinline__ int swz(int byteoff) {
    return byteoff ^ (((byteoff >> 7) & 7) << 4);
}
// async global->LDS, 16B per lane; LDS dest must be wave-uniform base
__device__ __forceinline__ void gl16(const u16* g, u16* l) {
    __builtin_amdgcn_global_load_lds(
        (const __attribute__((address_space(1))) unsigned*)(g),
        (__attribute__((address_space(3))) unsigned*)(l), 16, 0, 0);
}
__device__ __forceinline__ u32 cvtpk(float lo, float hi) {
    u32 r;
    asm("v_cvt_pk_bf16_f32 %0, %1, %2" : "=v"(r) : "v"(lo), "v"(hi));
    return r;
}
// (a,b) -> rows: a'=[a0,a2,b0,b2], b'=[a1,a3,b1,b3]  (16-lane rows)
__device__ __forceinline__ void plswap(u32& a, u32& b) {
    asm("v_permlane32_swap_b32 %0, %1" : "+v"(a), "+v"(b));
    asm("v_permlane16_swap_b32 %0, %1" : "+v"(a), "+v"(b));
}

// ---------------------------------------------------------------------------
// Weight packing: W[z][1024][64] -> out rows (voff + h*64 + k), cols d (bf16)
// ---------------------------------------------------------------------------
__global__ __launch_bounds__(256) void pack_wkv_t(const float* __restrict__ W,
                                                  u16* __restrict__ out, int voff) {
    __shared__ float tile[32][33];
    int z = blockIdx.z; int l = z >> 4, h = z & 15;
    const float* ip = W + (size_t)z * 1024 * 64;
    u16* op = out + (size_t)l * 2048 * 1024 + (size_t)(voff + h * 64) * 1024;
    int tx = threadIdx.x & 31, ty = threadIdx.x >> 5;
    int d0 = blockIdx.y * 32, k0 = blockIdx.x * 32;
#pragma unroll
    for (int j = 0; j < 32; j += 8)
        tile[ty + j][tx] = ip[(size_t)(d0 + ty + j) * 64 + k0 + tx];
    __syncthreads();
#pragma unroll
    for (int j = 0; j < 32; j += 8)
        op[(size_t)(k0 + ty + j) * 1024 + d0 + tx] = f2b(tile[tx][ty + j]);
}

__global__ __launch_bounds__(256) void transpose_cvt(const float* __restrict__ in,
                                                     u16* __restrict__ out, int R, int C) {
    __shared__ float tile[32][33];
    const float* ip = in + (size_t)blockIdx.z * R * C;
    u16* op = out + (size_t)blockIdx.z * R * C;
    int tx = threadIdx.x & 31, ty = threadIdx.x >> 5;
    int r0 = blockIdx.y * 32, c0 = blockIdx.x * 32;
#pragma unroll
    for (int j = 0; j < 32; j += 8)
        tile[ty + j][tx] = ip[(size_t)(r0 + ty + j) * C + c0 + tx];
    __syncthreads();
#pragma unroll
    for (int j = 0; j < 32; j += 8)
        op[(size_t)(c0 + ty + j) * R + r0 + tx] = f2b(tile[tx][ty + j]);
}

__global__ __launch_bounds__(256) void cvt_bf16(const float* __restrict__ in,
                                                u16* __restrict__ out, int n) {
    int i = (blockIdx.x * 256 + threadIdx.x) * 4;
    if (i >= n) return;
    float4 v = *(const float4*)&in[i];
    ushort4 o = {f2b(v.x), f2b(v.y), f2b(v.z), f2b(v.w)};
    *(ushort4*)&out[i] = o;
}

// ---------------------------------------------------------------------------
// GEMM: C[M][N] = A[M][K]bf16 @ B[N][K]bf16^T (+bias, epilogue)
// EPI 0: bf16 out (KV), K cols scaled by SCALEK; V^T tile to VTout
// EPI 1: bf16 out, bias + relu
// EPI 2: fp32 out, bias
// 128 x BN tile, BK=32, 4 waves; double-buffered global_load_lds prefetch
// ---------------------------------------------------------------------------
template <int EPI, int BN>
__global__ __launch_bounds__(256) void gemm_bt(const u16* __restrict__ A,
                                               const u16* __restrict__ B,
                                               const float* __restrict__ bias1,
                                               const float* __restrict__ bias2, int split,
                                               void* __restrict__ Cv,
                                               u16* __restrict__ VTout,
                                               int M, int N, int K) {
    constexpr int NB = BN / 32;
    constexpr int BCH = BN * 4;   // B chunks per k-step
    __shared__ __align__(16) u16 lA[2][512 * 8];
    __shared__ __align__(16) u16 lB[2][BCH * 8];
    const int t = threadIdx.x;
    const int lane = t & 63, w = t >> 6;
    const int wr = w >> 1, wc = w & 1;
    const int g = lane >> 4, r = lane & 15;
    const int m0 = blockIdx.y * 128, n0 = blockIdx.x * BN;

    const int c1 = w * 64 + lane;      // [0,256)
    const int c2 = 256 + c1;
    const u16* Ap1 = A + (size_t)(m0 + (c1 & 127)) * K + (c1 >> 7) * 8;
    const u16* Ap2 = A + (size_t)(m0 + (c2 & 127)) * K + (c2 >> 7) * 8;
    const u16* Bp1 = B + (size_t)(n0 + (c1 & (BN - 1))) * K + (c1 / BN) * 8;
    const u16* Bp2 = B + (size_t)(n0 + (c2 & (BN - 1))) * K + (c2 / BN) * 8;

    f32x4 zero4 = {0.f, 0.f, 0.f, 0.f};
    f32x4 acc[4][NB];
#pragma unroll
    for (int m = 0; m < 4; ++m)
#pragma unroll
        for (int n = 0; n < NB; ++n) acc[m][n] = zero4;

#define GSTAGE(bufi, k0)                                        \
    do {                                                        \
        gl16(Ap1 + (k0), &lA[bufi][(w * 64) * 8]);              \
        gl16(Ap2 + (k0), &lA[bufi][(256 + w * 64) * 8]);        \
        gl16(Bp1 + (k0), &lB[bufi][(w * 64) * 8]);              \
        if constexpr (BN == 128)                                \
            gl16(Bp2 + (k0), &lB[bufi][(256 + w * 64) * 8]);    \
    } while (0)

    GSTAGE(0, 0);
    __syncthreads();
    const int nk = K >> 5;
    for (int kt = 0; kt < nk; ++kt) {
        const int cur = kt & 1;
        if (kt + 1 < nk) GSTAGE(cur ^ 1, (kt + 1) * 32);
        short8 af[4], bf[NB];
#pragma unroll
        for (int m = 0; m < 4; ++m)
            af[m] = *(const short8*)&lA[cur][(g * 128 + wr * 64 + m * 16 + r) * 8];
#pragma unroll
        for (int n = 0; n < NB; ++n)
            bf[n] = *(const short8*)&lB[cur][(g * BN + wc * (BN / 2) + n * 16 + r) * 8];
#pragma unroll
        for (int m = 0; m < 4; ++m)
#pragma unroll
            for (int n = 0; n < NB; ++n)
                acc[m][n] = __builtin_amdgcn_mfma_f32_16x16x32_bf16(af[m], bf[n], acc[m][n], 0, 0, 0);
        __syncthreads();
    }
#undef GSTAGE

#pragma unroll
    for (int m = 0; m < 4; ++m) {
        int row = m0 + wr * 64 + m * 16 + g * 4;
#pragma unroll
        for (int n = 0; n < NB; ++n) {
            int col = n0 + wc * (BN / 2) + n * 16 + r;
            float bv_ = (col < split) ? bias1[col] : bias2[col - split];
            if (EPI == 0) {
                float sc = (col < split) ? SCALEK : 1.0f;
                ushort4 qv;
                qv.x = f2b((acc[m][n][0] + bv_) * sc);
                qv.y = f2b((acc[m][n][1] + bv_) * sc);
                qv.z = f2b((acc[m][n][2] + bv_) * sc);
                qv.w = f2b((acc[m][n][3] + bv_) * sc);
                u16* Cb = (u16*)Cv;
                Cb[(size_t)(row + 0) * N + col] = qv.x;
                Cb[(size_t)(row + 1) * N + col] = qv.y;
                Cb[(size_t)(row + 2) * N + col] = qv.z;
                Cb[(size_t)(row + 3) * N + col] = qv.w;
                if (col >= split) {
                    int d = col - split, b_ = row >> 10, s = row & 1023;
                    *(ushort4*)&VTout[(((size_t)(b_ * 16) + (d >> 6)) * 64 + (d & 63)) * 1024 + s] = qv;
                }
            } else if (EPI == 1) {
                u16* Cb = (u16*)Cv;
#pragma unroll
                for (int i = 0; i < 4; ++i)
                    Cb[(size_t)(row + i) * N + col] = f2b(fmaxf(acc[m][n][i] + bv_, 0.f));
            } else {
#pragma unroll
                for (int i = 0; i < 4; ++i)
                    ((float*)Cv)[(size_t)(row + i) * N + col] = acc[m][n][i] + bv_;
            }
        }
    }
}

// ---------------------------------------------------------------------------
// Flash attention, swapped-QK^T in-register softmax (T12), 8 waves x 16 q-rows
// KV[token][0..1023]=K-proj (pre-scaled SCALEK), [1024..2047]=V-proj
// VT[b][h][d][token]=V^T. Grid 512: XCD-chunked so one (b,h) stays on one XCD.
// Per tile: S^T=mfma(K,Q) -> lane holds P-row for q=r; softmax in-reg;
// P->bf16 via cvt_pk + permlane swaps -> PV A-operand; dbuf prefetch staging.
// ---------------------------------------------------------------------------
__global__ __launch_bounds__(512) void attn_kernel(const u16* __restrict__ KV,
                                                   const u16* __restrict__ VT,
                                                   u16* __restrict__ Out) {
    __shared__ __align__(16) u16 kt[2][512 * 8];
    __shared__ __align__(16) u16 vt[2][512 * 8];
    const int t = threadIdx.x;
    const int lane = t & 63, w = t >> 6;
    const int g = lane >> 4, r = lane & 15;
    const int d0 = blockIdx.x;
    const int q = d0 >> 3;
    const int bh = (d0 & 7) * 8 + (q >> 3), qb = q & 7;
    const int h = bh & 15, b = bh >> 4;
    const u16* Kbase = KV + (size_t)b * 1024 * 2048 + h * 64;
    const u16* Vbase = Kbase + 1024;
    const u16* VTbase = VT + ((size_t)(b * 16 + h)) * 64 * 1024;

    // loop-invariant Q fragments (B-operand): Q[q=w*16+r][ks*32+g*8..+7]
    const int qrow = qb * 128 + w * 16 + r;
    const short8 qf0 = *(const short8*)&Kbase[(size_t)qrow * 2048 + g * 8];
    const short8 qf1 = *(const short8*)&Kbase[(size_t)qrow * 2048 + 32 + g * 8];

    // staging: 512 chunks per tile, 1 per thread; source col pre-swizzled
    const int row = t >> 3;
    const int colu = (((t & 7) * 16) ^ ((row & 7) << 4)) >> 1;
    const u16* Ksrc = Vbase + (size_t)row * 2048 + colu;   // V-proj = keys
    const u16* Vsrc = VTbase + (size_t)row * 1024 + colu;  // V^T = values

#define STAGE(bufi, t0)                                   \
    do {                                                  \
        gl16(Ksrc + (size_t)(t0) * 2048, &kt[bufi][(w * 64) * 8]); \
        gl16(Vsrc + (t0), &vt[bufi][(w * 64) * 8]);       \
    } while (0)

    STAGE(0, 0);

    float m = -1e30f, l = 0.f;
    f32x4 zero4 = {0.f, 0.f, 0.f, 0.f};
    f32x4 oacc[4];
#pragma unroll
    for (int n = 0; n < 4; ++n) oacc[n] = zero4;
    const int cbase = (lane & 48) | (g << 2);  // src lane holding row 4g+i data
    __syncthreads();

    for (int tt = 0; tt < 16; ++tt) {
        const int cur = tt & 1;
        if (tt < 15) STAGE(cur ^ 1, (tt + 1) * 64);
        const char* kbuf = (const char*)&kt[cur][0];
        const char* vbuf = (const char*)&vt[cur][0];

        // S^T[key][q]: sfT[n][i] = S[key=n*16+g*4+i][q-row r]
        f32x4 sfT[4];
#pragma unroll
        for (int n = 0; n < 4; ++n) sfT[n] = zero4;
#pragma unroll
        for (int ks = 0; ks < 2; ++ks) {
            const short8 qf = ks ? qf1 : qf0;
#pragma unroll
            for (int n = 0; n < 4; ++n) {
                short8 kf = *(const short8*)(kbuf + swz((n * 16 + r) * 128 + ks * 64 + g * 16));
                sfT[n] = __builtin_amdgcn_mfma_f32_16x16x32_bf16(kf, qf, sfT[n], 0, 0, 0);
            }
        }
        // row max: 15 in-lane + 2 shfl over g
        float rm = fmaxf(fmaxf(sfT[0][0], sfT[0][1]), fmaxf(sfT[0][2], sfT[0][3]));
        float r1 = fmaxf(fmaxf(sfT[1][0], sfT[1][1]), fmaxf(sfT[1][2], sfT[1][3]));
        float r2 = fmaxf(fmaxf(sfT[2][0], sfT[2][1]), fmaxf(sfT[2][2], sfT[2][3]));
        float r3 = fmaxf(fmaxf(sfT[3][0], sfT[3][1]), fmaxf(sfT[3][2], sfT[3][3]));
        rm = fmaxf(fmaxf(rm, r1), fmaxf(r2, r3));
        rm = fmaxf(rm, __shfl_xor(rm, 16, 64));
        rm = fmaxf(rm, __shfl_xor(rm, 32, 64));
        // defer-max (T13): skip O/l rescale while max growth <= 8 (log2 domain)
        if (!__all(rm <= m + 8.f)) {
            float mn = fmaxf(m, rm);
            float cc = EXP2(m - mn);
            m = mn;
            l *= cc;
#pragma unroll
            for (int i = 0; i < 4; ++i) {
                float ci = __shfl(cc, cbase + i, 64);
#pragma unroll
                for (int n = 0; n < 4; ++n) oacc[n][i] *= ci;
            }
        }
        float rs = 0.f;
#pragma unroll
        for (int n = 0; n < 4; ++n)
#pragma unroll
            for (int i = 0; i < 4; ++i) {
                float p = EXP2(sfT[n][i] - m);
                sfT[n][i] = p;
                rs += p;
            }
        rs += __shfl_xor(rs, 16, 64);
        rs += __shfl_xor(rs, 32, 64);
        l += rs;
        // pack P to bf16 words: wpk[n][h2] = keys n*16+g*4+2h2, +2h2+1
        u32 wpk[4][2];
#pragma unroll
        for (int n = 0; n < 4; ++n) {
            wpk[n][0] = cvtpk(sfT[n][0], sfT[n][1]);
            wpk[n][1] = cvtpk(sfT[n][2], sfT[n][3]);
        }
        // PV: assemble A-frag (P[q=r][32-key slice]) via permlane swaps
#pragma unroll
        for (int ks = 0; ks < 2; ++ks) {
            u32 a0 = wpk[2 * ks][0], a2 = wpk[2 * ks + 1][0];
            plswap(a0, a2);
            u32 a1 = wpk[2 * ks][1], a3 = wpk[2 * ks + 1][1];
            plswap(a1, a3);
            uint4 av;
            av.x = a0; av.y = a1; av.z = a2; av.w = a3;
            union { uint4 u; short8 s; } uc;
            uc.u = av;
            const short8 af = uc.s;
#pragma unroll
            for (int n = 0; n < 4; ++n) {
                short8 vf = *(const short8*)(vbuf + swz((n * 16 + r) * 128 + ks * 64 + g * 16));
                oacc[n] = __builtin_amdgcn_mfma_f32_16x16x32_bf16(af, vf, oacc[n], 0, 0, 0);
            }
        }
        __syncthreads();
    }
#undef STAGE

#pragma unroll
    for (int i = 0; i < 4; ++i) {
        float li = 1.f / __shfl(l, cbase + i, 64);
        int orow = b * 1024 + qb * 128 + w * 16 + g * 4 + i;
#pragma unroll
        for (int n = 0; n < 4; ++n)
            Out[(size_t)orow * 1024 + h * 64 + n * 16 + r] = f2b(oacc[n][i] * li);
    }
}

// ---------------------------------------------------------------------------
// Fused residual + LayerNorm, all-bf16 I/O, f32 math
// ---------------------------------------------------------------------------
__global__ __launch_bounds__(256) void ln_kernel(const u16* __restrict__ xin,
                                                 const u16* __restrict__ addin,
                                                 const float* __restrict__ gamma,
                                                 const float* __restrict__ beta,
                                                 u16* __restrict__ xbout) {
    const int row = blockIdx.x, t = threadIdx.x;
    const size_t base = (size_t)row * 1024;
    ushort4 xu = *(const ushort4*)&xin[base + t * 4];
    ushort4 au = *(const ushort4*)&addin[base + t * 4];
    float v0 = b2f(xu.x) + b2f(au.x), v1 = b2f(xu.y) + b2f(au.y);
    float v2 = b2f(xu.z) + b2f(au.z), v3 = b2f(xu.w) + b2f(au.w);
    float s = v0 + v1 + v2 + v3;
    __shared__ float red[4];
    const int lane = t & 63, w = t >> 6;
#pragma unroll
    for (int off = 32; off; off >>= 1) s += __shfl_xor(s, off, 64);
    if (lane == 0) red[w] = s;
    __syncthreads();
    float mean = (red[0] + red[1] + red[2] + red[3]) * (1.f / 1024.f);
    __syncthreads();
    float d0 = v0 - mean, d1 = v1 - mean, d2 = v2 - mean, d3 = v3 - mean;
    float sq = d0 * d0 + d1 * d1 + d2 * d2 + d3 * d3;
#pragma unroll
    for (int off = 32; off; off >>= 1) sq += __shfl_xor(sq, off, 64);
    if (lane == 0) red[w] = sq;
    __syncthreads();
    float var = (red[0] + red[1] + red[2] + red[3]) * (1.f / 1024.f);
    float rstd = rsqrtf(var + 1e-5f);
    float4 gv = *(const float4*)&gamma[t * 4];
    float4 bv = *(const float4*)&beta[t * 4];
    ushort4 o;
    o.x = f2b(d0 * rstd * gv.x + bv.x);
    o.y = f2b(d1 * rstd * gv.y + bv.y);
    o.z = f2b(d2 * rstd * gv.z + bv.z);
    o.w = f2b(d3 * rstd * gv.w + bv.w);
    *(ushort4*)&xbout[base + t * 4] = o;
}

// ---------------------------------------------------------------------------
extern "C" void kernel_launch(void* const* d_in, const int* in_sizes, int n_in,
                              void* d_out, int out_size, void* d_ws, size_t ws_size,
                              hipStream_t stream) {
    const float* x  = (const float*)d_in[0];
    const float* Wk = (const float*)d_in[1];
    const float* bk = (const float*)d_in[2];
    const float* Wv = (const float*)d_in[3];
    const float* bv = (const float*)d_in[4];
    const float* Wl = (const float*)d_in[5];
    const float* bl = (const float*)d_in[6];
    const float* g1 = (const float*)d_in[7];
    const float* b1 = (const float*)d_in[8];
    const float* g2 = (const float*)d_in[9];
    const float* b2 = (const float*)d_in[10];
    const float* Wo = (const float*)d_in[11];
    const float* bo = (const float*)d_in[12];

    char* ws = (char*)d_ws;
    u16* Wkvb = (u16*)ws;  ws += (size_t)4 * 2048 * 1024 * 2;   // 16 MB
    u16* Wlb  = (u16*)ws;  ws += (size_t)4 * 1024 * 1024 * 2;   //  8 MB
    u16* Wob  = (u16*)ws;  ws += (size_t)1024 * 1024 * 2;       //  2 MB
    u16* xb   = (u16*)ws;  ws += (size_t)4096 * 1024 * 2;       //  8 MB
    u16* KVb  = (u16*)ws;  ws += (size_t)4096 * 2048 * 2;       // 16 MB
    u16* VTb  = (u16*)ws;  ws += (size_t)4096 * 1024 * 2;       //  8 MB
    u16* tmpb = (u16*)ws;  ws += (size_t)4096 * 1024 * 2;       //  8 MB

    pack_wkv_t<<<dim3(2, 32, 64), 256, 0, stream>>>(Wk, Wkvb, 0);
    pack_wkv_t<<<dim3(2, 32, 64), 256, 0, stream>>>(Wv, Wkvb, 1024);
    transpose_cvt<<<dim3(32, 32, 4), 256, 0, stream>>>(Wl, Wlb, 1024, 1024);
    transpose_cvt<<<dim3(32, 32, 1), 256, 0, stream>>>(Wo, Wob, 1024, 1024);
    cvt_bf16<<<dim3(4096), 256, 0, stream>>>(x, xb, 4096 * 1024);

    for (int l = 0; l < 4; ++l) {
        gemm_bt<0, 128><<<dim3(16, 32), 256, 0, stream>>>(
            xb, Wkvb + (size_t)l * 2048 * 1024, bk + l * 1024, bv + l * 1024, 1024,
            (void*)KVb, VTb, 4096, 2048, 1024);
        attn_kernel<<<dim3(512), 512, 0, stream>>>(KVb, VTb, tmpb);
        ln_kernel<<<dim3(4096), 256, 0, stream>>>(
            xb, tmpb, g1 + l * 1024, b1 + l * 1024, xb);
        gemm_bt<1, 64><<<dim3(16, 32), 256, 0, stream>>>(
            xb, Wlb + (size_t)l * 1024 * 1024, bl + l * 1024, bl + l * 1024, 1024,
            (void*)tmpb, nullptr, 4096, 1024, 1024);
        ln_kernel<<<dim3(4096), 256, 0, stream>>>(
            xb, tmpb, g2 + l * 1024, b2 + l * 1024, xb);
    }
    gemm_bt<2, 64><<<dim3(16, 32), 256, 0, stream>>>(
        xb, Wob, bo, bo, 1024, d_out, nullptr, 4096, 1024, 1024);
}